// Round 1
// baseline (3151.522 us; speedup 1.0000x reference)
//
#include <hip/hip_runtime.h>
#include <stdint.h>

typedef uint32_t u32;
typedef uint64_t u64;

#define CONF_THRESH 0.5f
#define PIOU_THRESH 0.5f

// ---------------------------------------------------------------------------
// K1a: rank by (conf desc, idx asc) via O(N^2) counting. key = conf_bits<<32 | ~idx.
// conf >= 0 so float bits are order-preserving. Stable tie-break matches
// jnp.argsort(-conf) (stable) semantics.
// ---------------------------------------------------------------------------
__global__ void rank_kernel(const float* __restrict__ in, u32* __restrict__ rank, int N) {
    __shared__ u64 keys[2048];
    int t = threadIdx.x;
    int i = blockIdx.x * 256 + t;
    int j0 = blockIdx.y * 2048;
    for (int k = t; k < 2048; k += 256) {
        int j = j0 + k;
        u64 key = 0;  // smaller than any real key -> never counted
        if (j < N) {
            u32 cb = __float_as_uint(in[(size_t)j * 5]);
            key = ((u64)cb << 32) | (u64)(0xFFFFFFFFu - (u32)j);
        }
        keys[k] = key;
    }
    __syncthreads();
    if (i >= N) return;
    u32 cbi = __float_as_uint(in[(size_t)i * 5]);
    u64 mykey = ((u64)cbi << 32) | (u64)(0xFFFFFFFFu - (u32)i);
    int cnt = 0;
    for (int k = 0; k < 2048; ++k) cnt += (keys[k] > mykey) ? 1 : 0;
    if (cnt) atomicAdd(&rank[i], (u32)cnt);
}

// ---------------------------------------------------------------------------
// K1b: scatter boxes into sorted order (geometry only) + count valid M.
// ---------------------------------------------------------------------------
__global__ void scatter_kernel(const float* __restrict__ in, const u32* __restrict__ rank,
                               float4* __restrict__ sbox, u32* __restrict__ Mctr, int N) {
    int i = blockIdx.x * 256 + threadIdx.x;
    if (i >= N) return;
    float c = in[(size_t)i * 5 + 0];
    float s = in[(size_t)i * 5 + 1];
    float e = in[(size_t)i * 5 + 2];
    float p = in[(size_t)i * 5 + 3];
    float h = in[(size_t)i * 5 + 4];
    u32 r = rank[i];
    sbox[r] = make_float4(s, e, p, h);
    if (c > CONF_THRESH) atomicAdd(Mctr, 1u);
}

// ---------------------------------------------------------------------------
// K2: suppression bit matrix. mask[i][w] bit b: j = 64w+b, set iff
// j>i && j<M && piou(sorted_i, sorted_j) > 0.5. Row stride = WROW words.
// One wave per (i-tile, word): lanes hold box j; loop over 64 rows; ballot packs.
// ---------------------------------------------------------------------------
__global__ void mask_kernel(const float4* __restrict__ sbox, const u32* __restrict__ Mptr,
                            u64* __restrict__ mask, int N, int WROW) {
#pragma clang fp contract(off)
    int M = (int)*Mptr;
    int Wm = (M + 63) >> 6;
    int wave = threadIdx.x >> 6;
    int lane = threadIdx.x & 63;
    int i0 = blockIdx.x * 64;
    int w = blockIdx.y * 4 + wave;
    if (i0 >= M || w >= Wm) return;

    int j = w * 64 + lane;           // j < Wm*64 <= N: safe to load
    float4 bj = sbox[j];
    float area2 = (bj.y - bj.x) * bj.w;
    int imax = min(64, M - i0);
    for (int it = 0; it < imax; ++it) {
        int i = i0 + it;
        float4 bi = sbox[i];         // uniform across the wave
        float inter_start = fmaxf(bi.x, bj.x);
        float inter_end   = fminf(bi.y, bj.y);
        float inter_len   = fmaxf(inter_end - inter_start, 0.0f);
        float inter_h     = fminf(bi.w, bj.w);
        float inter_area  = inter_len * inter_h;
        float area1       = (bi.y - bi.x) * bi.w;
        float union_area  = area1 + area2 - inter_area;
        float iou         = inter_area / union_area;
        float peak_dist   = fabsf(bi.z - bj.z);
        float union_start = fminf(bi.x, bj.x);
        float union_end   = fmaxf(bi.y, bj.y);
        float union_dist  = fabsf(union_end - union_start);
        float piou        = iou - peak_dist / union_dist;
        bool bit = (j < M) && (j > i) && (piou > PIOU_THRESH);
        u64 bal = __ballot(bit);
        if (lane == 0) mask[(size_t)i * WROW + w] = bal;
    }
}

// ---------------------------------------------------------------------------
// K3: sequential greedy resolution, single wave. Removed bitset R (256 words,
// 4/lane: word w -> lane w&63, slot w>>6). Per 64-rank chunk: gather intra
// matrix (1 load/lane), unrolled 64-step scalar resolution, OR kept rows.
// ---------------------------------------------------------------------------
__device__ inline u64 shfl64(u64 v, int src) {
    int lo = __shfl((int)(u32)v, src, 64);
    int hi = __shfl((int)(u32)(v >> 32), src, 64);
    return ((u64)(u32)hi << 32) | (u32)lo;
}

__global__ void __launch_bounds__(64) nms_seq_kernel(const u64* __restrict__ mask,
                                                     const u32* __restrict__ Mptr,
                                                     u64* __restrict__ keepm, int WROW) {
    int lane = threadIdx.x;
    int M = (int)*Mptr;
    int Wm = (M + 63) >> 6;
    u64 R0 = 0, R1 = 0, R2 = 0, R3 = 0;   // removed bits
    u64 K0 = 0, K1 = 0, K2 = 0, K3 = 0;   // keep bits

    for (int c = 0; c < Wm; ++c) {
        // intra-chunk matrix: lane b holds row (64c+b)'s word c
        int row = c * 64 + lane;
        u64 m = 0;
        if (row < M) m = mask[(size_t)row * WROW + c];

        // prior removed bits for this chunk's 64 ranks = R word c
        int slot = c >> 6, src = c & 63;
        u64 Rs = (slot == 0) ? R0 : (slot == 1) ? R1 : (slot == 2) ? R2 : R3;
        u64 removed = shfl64(Rs, src);
        u64 kept = 0;

#pragma unroll
        for (int b = 0; b < 64; ++b) {
            u32 mlo = __builtin_amdgcn_readlane((u32)m, b);
            u32 mhi = __builtin_amdgcn_readlane((u32)(m >> 32), b);
            u64 mb = ((u64)mhi << 32) | mlo;
            u64 isrem = (removed >> b) & 1ull;
            kept |= (1ull - isrem) << b;
            removed |= mb & (isrem - 1ull);   // OR row only if not removed
        }
        int rem = M - c * 64;
        if (rem < 64) kept &= (1ull << rem) - 1ull;

        u64 contrib = (lane == src) ? kept : 0ull;
        if (slot == 0) K0 |= contrib;
        else if (slot == 1) K1 |= contrib;
        else if (slot == 2) K2 |= contrib;
        else K3 |= contrib;

        // OR full rows of kept boxes into R
        u64 kk = kept;
        while (kk) {
            int b = __builtin_ctzll(kk);
            kk &= kk - 1;
            const u64* rowp = mask + (size_t)(c * 64 + b) * WROW;
            if (lane < Wm)        R0 |= rowp[lane];
            if (lane + 64 < Wm)   R1 |= rowp[lane + 64];
            if (lane + 128 < Wm)  R2 |= rowp[lane + 128];
            if (lane + 192 < Wm)  R3 |= rowp[lane + 192];
        }
    }
    keepm[lane]       = K0;
    keepm[lane + 64]  = K1;
    keepm[lane + 128] = K2;
    keepm[lane + 192] = K3;
}

// ---------------------------------------------------------------------------
// K4: out[r] = sorted geometry * keep bit (exact 0/1 multiply).
// ---------------------------------------------------------------------------
__global__ void out_kernel(const float4* __restrict__ sbox, const u64* __restrict__ keepm,
                           float4* __restrict__ out, int N) {
    int r = blockIdx.x * 256 + threadIdx.x;
    if (r >= N) return;
    u64 w = keepm[r >> 6];
    float k = (float)((w >> (r & 63)) & 1ull);
    float4 v = sbox[r];
    out[r] = make_float4(v.x * k, v.y * k, v.z * k, v.w * k);
}

// ---------------------------------------------------------------------------
extern "C" void kernel_launch(void* const* d_in, const int* in_sizes, int n_in,
                              void* d_out, int out_size, void* d_ws, size_t ws_size,
                              hipStream_t stream) {
    const float* in = (const float*)d_in[0];
    int N = in_sizes[0] / 5;          // 16384
    int WROW = (N + 63) >> 6;         // 256 words per mask row

    char* ws = (char*)d_ws;
    u64* mask = (u64*)ws;                                   // N * WROW * 8 = 32 MB
    size_t maskBytes = (size_t)N * WROW * sizeof(u64);
    float4* sbox = (float4*)(ws + maskBytes);               // N * 16 = 256 KB
    u64* keepm = (u64*)(ws + maskBytes + (size_t)N * 16);   // WROW * 8 = 2 KB
    u32* rank = (u32*)(ws + maskBytes + (size_t)N * 16 + (size_t)WROW * 8);  // N * 4
    u32* Mctr = rank + N;                                   // 4 B

    // zero rank + M counter (ws is poisoned 0xAA before each call)
    hipMemsetAsync(rank, 0, (size_t)N * sizeof(u32) + sizeof(u32), stream);

    dim3 rgrid(N / 256, N / 2048);
    rank_kernel<<<rgrid, 256, 0, stream>>>(in, rank, N);

    scatter_kernel<<<N / 256, 256, 0, stream>>>(in, rank, sbox, Mctr, N);

    dim3 mgrid(N / 64, (WROW + 3) / 4);
    mask_kernel<<<mgrid, 256, 0, stream>>>(sbox, Mctr, mask, N, WROW);

    nms_seq_kernel<<<1, 64, 0, stream>>>(mask, Mctr, keepm, WROW);

    out_kernel<<<N / 256, 256, 0, stream>>>(sbox, keepm, (float4*)d_out, N);
}

// Round 2
// 638.562 us; speedup vs baseline: 4.9353x; 4.9353x over previous
//
#include <hip/hip_runtime.h>
#include <stdint.h>

typedef uint32_t u32;
typedef uint64_t u64;

#define CONF_THRESH 0.5f
#define PIOU_THRESH 0.5f

// ---------------------------------------------------------------------------
// K1a: rank by (conf desc, idx asc) via O(N^2) counting. key = conf_bits<<32 | ~idx.
// conf >= 0 so float bits are order-preserving. Stable tie-break matches
// jnp.argsort(-conf) (stable) semantics.
// ---------------------------------------------------------------------------
__global__ void rank_kernel(const float* __restrict__ in, u32* __restrict__ rank, int N) {
    __shared__ u64 keys[2048];
    int t = threadIdx.x;
    int i = blockIdx.x * 256 + t;
    int j0 = blockIdx.y * 2048;
    for (int k = t; k < 2048; k += 256) {
        int j = j0 + k;
        u64 key = 0;  // smaller than any real key -> never counted
        if (j < N) {
            u32 cb = __float_as_uint(in[(size_t)j * 5]);
            key = ((u64)cb << 32) | (u64)(0xFFFFFFFFu - (u32)j);
        }
        keys[k] = key;
    }
    __syncthreads();
    if (i >= N) return;
    u32 cbi = __float_as_uint(in[(size_t)i * 5]);
    u64 mykey = ((u64)cbi << 32) | (u64)(0xFFFFFFFFu - (u32)i);
    int cnt = 0;
    for (int k = 0; k < 2048; ++k) cnt += (keys[k] > mykey) ? 1 : 0;
    if (cnt) atomicAdd(&rank[i], (u32)cnt);
}

// ---------------------------------------------------------------------------
// K1b: scatter boxes into sorted order (geometry only) + count valid M.
// ---------------------------------------------------------------------------
__global__ void scatter_kernel(const float* __restrict__ in, const u32* __restrict__ rank,
                               float4* __restrict__ sbox, u32* __restrict__ Mctr, int N) {
    int i = blockIdx.x * 256 + threadIdx.x;
    if (i >= N) return;
    float c = in[(size_t)i * 5 + 0];
    float s = in[(size_t)i * 5 + 1];
    float e = in[(size_t)i * 5 + 2];
    float p = in[(size_t)i * 5 + 3];
    float h = in[(size_t)i * 5 + 4];
    u32 r = rank[i];
    sbox[r] = make_float4(s, e, p, h);
    if (c > CONF_THRESH) atomicAdd(Mctr, 1u);
}

// ---------------------------------------------------------------------------
// K2: suppression bit matrix. mask[i][w] bit b: j = 64w+b, set iff
// j>i && j<M && piou(sorted_i, sorted_j) > 0.5. Row stride = WROW words.
// Lower triangle (w < i/64) is all-zero and never read -> skip those blocks.
// ---------------------------------------------------------------------------
__global__ void mask_kernel(const float4* __restrict__ sbox, const u32* __restrict__ Mptr,
                            u64* __restrict__ mask, int N, int WROW) {
#pragma clang fp contract(off)
    int M = (int)*Mptr;
    int Wm = (M + 63) >> 6;
    int wave = threadIdx.x >> 6;
    int lane = threadIdx.x & 63;
    int i0 = blockIdx.x * 64;
    int w = blockIdx.y * 4 + wave;
    if (i0 >= M || w >= Wm) return;
    if (w < (int)blockIdx.x) return;   // lower triangle: all zero, never read

    int j = w * 64 + lane;           // j < Wm*64 <= N: safe to load
    float4 bj = sbox[j];
    float area2 = (bj.y - bj.x) * bj.w;
    int imax = min(64, M - i0);
    for (int it = 0; it < imax; ++it) {
        int i = i0 + it;
        float4 bi = sbox[i];         // uniform across the wave
        float inter_start = fmaxf(bi.x, bj.x);
        float inter_end   = fminf(bi.y, bj.y);
        float inter_len   = fmaxf(inter_end - inter_start, 0.0f);
        float inter_h     = fminf(bi.w, bj.w);
        float inter_area  = inter_len * inter_h;
        float area1       = (bi.y - bi.x) * bi.w;
        float union_area  = area1 + area2 - inter_area;
        float iou         = inter_area / union_area;
        float peak_dist   = fabsf(bi.z - bj.z);
        float union_start = fminf(bi.x, bj.x);
        float union_end   = fmaxf(bi.y, bj.y);
        float union_dist  = fabsf(union_end - union_start);
        float piou        = iou - peak_dist / union_dist;
        bool bit = (j < M) && (j > i) && (piou > PIOU_THRESH);
        u64 bal = __ballot(bit);
        if (lane == 0) mask[(size_t)i * WROW + w] = bal;
    }
}

// ---------------------------------------------------------------------------
// K3: sequential greedy resolution. ONE workgroup, 16 waves (1024 threads).
// LDS removed-bitset R (512 u32). Per 64-rank chunk:
//   wave 0: scalar set-bit resolution loop (only alive boxes, readlane rows)
//   all waves: cooperative OR of kept rows' words (w > c) into LDS R
//   wave 1: prefetch next chunk's 64x64 diagonal block into LDS (off crit path)
// ---------------------------------------------------------------------------
__global__ void __launch_bounds__(1024) nms_seq_kernel(const u64* __restrict__ mask,
                                                       const u32* __restrict__ Mptr,
                                                       u64* __restrict__ keepm, int WROW) {
    __shared__ u32 R32[512];          // removed bitset, 2 u32 per 64-bit word
    __shared__ u64 ddiag[2][64];      // double-buffered diagonal block
    __shared__ u32 rows_l[64];        // kept row ids for OR phase
    __shared__ u32 kcnt;              // number of kept rows this chunk

    int tid = threadIdx.x;
    int M = (int)*Mptr;
    int Wm = (M + 63) >> 6;

    // init LDS
    if (tid < 512) R32[tid] = 0;
    if (tid < 64) {
        int row = tid;
        ddiag[0][tid] = (row < M) ? mask[(size_t)row * WROW + 0] : 0ull;
    }
    __syncthreads();

    for (int c = 0; c < Wm; ++c) {
        // ---- wave 0: resolve chunk c ----
        if (tid < 64) {
            u64 m = ddiag[c & 1][tid];                 // my row's diag word
            u64 removed = ((u64)R32[2 * c + 1] << 32) | (u64)R32[2 * c];
            int rem = M - c * 64;
            u64 validm = (rem >= 64) ? ~0ull : ((1ull << rem) - 1ull);
            u64 alive = ~removed & validm;
            u64 kept = 0;
            while (alive) {
                int b = __builtin_ctzll(alive);
                kept |= 1ull << b;
                u32 mlo = __builtin_amdgcn_readlane((u32)m, b);
                u32 mhi = __builtin_amdgcn_readlane((u32)(m >> 32), b);
                u64 mb = ((u64)mhi << 32) | mlo;
                alive &= ~(mb | (1ull << b));
            }
            // emit kept row list + count + keep word
            u32 prefix = (u32)__builtin_popcountll(kept & ((1ull << tid) - 1ull));
            if ((kept >> tid) & 1ull) rows_l[prefix] = (u32)(c * 64 + tid);
            if (tid == 0) {
                kcnt = (u32)__builtin_popcountll(kept);
                keepm[c] = kept;
            }
        }
        __syncthreads();

        // ---- wave 1: prefetch next diagonal block ----
        if (tid >= 64 && tid < 128 && (c + 1) < Wm) {
            int row = (c + 1) * 64 + (tid - 64);
            ddiag[(c + 1) & 1][tid - 64] = (row < M) ? mask[(size_t)row * WROW + (c + 1)] : 0ull;
        }

        // ---- all waves: OR kept rows' words (c+1 .. Wm-1) into R ----
        int K = (int)kcnt;
        int cnt = Wm - 1 - c;
        int total = K * cnt;
        for (int idx = tid; idx < total; idx += 1024) {
            int k = idx / cnt;
            int w = c + 1 + (idx - k * cnt);
            u64 v = mask[(size_t)rows_l[k] * WROW + w];
            if (v) {
                atomicOr(&R32[2 * w],     (u32)v);
                atomicOr(&R32[2 * w + 1], (u32)(v >> 32));
            }
        }
        __syncthreads();
    }
}

// ---------------------------------------------------------------------------
// K4: out[r] = sorted geometry * keep bit (exact 0/1 multiply).
// ---------------------------------------------------------------------------
__global__ void out_kernel(const float4* __restrict__ sbox, const u64* __restrict__ keepm,
                           float4* __restrict__ out, int N) {
    int r = blockIdx.x * 256 + threadIdx.x;
    if (r >= N) return;
    u64 w = keepm[r >> 6];
    float k = (float)((w >> (r & 63)) & 1ull);
    float4 v = sbox[r];
    out[r] = make_float4(v.x * k, v.y * k, v.z * k, v.w * k);
}

// ---------------------------------------------------------------------------
extern "C" void kernel_launch(void* const* d_in, const int* in_sizes, int n_in,
                              void* d_out, int out_size, void* d_ws, size_t ws_size,
                              hipStream_t stream) {
    const float* in = (const float*)d_in[0];
    int N = in_sizes[0] / 5;          // 16384
    int WROW = (N + 63) >> 6;         // 256 words per mask row

    char* ws = (char*)d_ws;
    u64* mask = (u64*)ws;                                   // N * WROW * 8 = 32 MB
    size_t maskBytes = (size_t)N * WROW * sizeof(u64);
    float4* sbox = (float4*)(ws + maskBytes);               // N * 16 = 256 KB
    u64* keepm = (u64*)(ws + maskBytes + (size_t)N * 16);   // WROW * 8 = 2 KB
    u32* rank = (u32*)((char*)keepm + (size_t)WROW * 8);    // N * 4
    u32* Mctr = rank + N;                                   // 4 B

    // zero keepm + rank + Mctr in one contiguous memset (ws is poisoned 0xAA)
    hipMemsetAsync(keepm, 0, (size_t)WROW * 8 + (size_t)N * 4 + 4, stream);

    dim3 rgrid(N / 256, N / 2048);
    rank_kernel<<<rgrid, 256, 0, stream>>>(in, rank, N);

    scatter_kernel<<<N / 256, 256, 0, stream>>>(in, rank, sbox, Mctr, N);

    dim3 mgrid(N / 64, (WROW + 3) / 4);
    mask_kernel<<<mgrid, 256, 0, stream>>>(sbox, Mctr, mask, N, WROW);

    nms_seq_kernel<<<1, 1024, 0, stream>>>(mask, Mctr, keepm, WROW);

    out_kernel<<<N / 256, 256, 0, stream>>>(sbox, keepm, (float4*)d_out, N);
}

// Round 3
// 606.433 us; speedup vs baseline: 5.1968x; 1.0530x over previous
//
#include <hip/hip_runtime.h>
#include <stdint.h>

typedef uint32_t u32;
typedef uint64_t u64;

#define CONF_THRESH 0.5f
#define PIOU_THRESH 0.5f

// ---------------------------------------------------------------------------
// K1a: rank by (conf desc, idx asc) via O(N^2) counting. key = conf_bits<<32 | ~idx.
// conf >= 0 so float bits are order-preserving. Stable tie-break matches
// jnp.argsort(-conf) (stable) semantics.
// ---------------------------------------------------------------------------
__global__ void rank_kernel(const float* __restrict__ in, u32* __restrict__ rank, int N) {
    __shared__ u64 keys[2048];
    int t = threadIdx.x;
    int i = blockIdx.x * 256 + t;
    int j0 = blockIdx.y * 2048;
    for (int k = t; k < 2048; k += 256) {
        int j = j0 + k;
        u64 key = 0;  // smaller than any real key -> never counted
        if (j < N) {
            u32 cb = __float_as_uint(in[(size_t)j * 5]);
            key = ((u64)cb << 32) | (u64)(0xFFFFFFFFu - (u32)j);
        }
        keys[k] = key;
    }
    __syncthreads();
    if (i >= N) return;
    u32 cbi = __float_as_uint(in[(size_t)i * 5]);
    u64 mykey = ((u64)cbi << 32) | (u64)(0xFFFFFFFFu - (u32)i);
    int cnt = 0;
    for (int k = 0; k < 2048; ++k) cnt += (keys[k] > mykey) ? 1 : 0;
    if (cnt) atomicAdd(&rank[i], (u32)cnt);
}

// ---------------------------------------------------------------------------
// K1b: scatter boxes into sorted order (geometry only) + count valid M.
// ---------------------------------------------------------------------------
__global__ void scatter_kernel(const float* __restrict__ in, const u32* __restrict__ rank,
                               float4* __restrict__ sbox, u32* __restrict__ Mctr, int N) {
    int i = blockIdx.x * 256 + threadIdx.x;
    if (i >= N) return;
    float c = in[(size_t)i * 5 + 0];
    float s = in[(size_t)i * 5 + 1];
    float e = in[(size_t)i * 5 + 2];
    float p = in[(size_t)i * 5 + 3];
    float h = in[(size_t)i * 5 + 4];
    u32 r = rank[i];
    sbox[r] = make_float4(s, e, p, h);
    if (c > CONF_THRESH) atomicAdd(Mctr, 1u);
}

// ---------------------------------------------------------------------------
// K2: suppression bit matrix. mask[i][w] bit b: j = 64w+b, set iff
// j>i && j<M && piou(sorted_i, sorted_j) > 0.5. Row stride = WROW words.
// Lower triangle (w < i/64) is all-zero and never read -> skip those blocks.
// ---------------------------------------------------------------------------
__global__ void mask_kernel(const float4* __restrict__ sbox, const u32* __restrict__ Mptr,
                            u64* __restrict__ mask, int N, int WROW) {
#pragma clang fp contract(off)
    int M = (int)*Mptr;
    int Wm = (M + 63) >> 6;
    int wave = threadIdx.x >> 6;
    int lane = threadIdx.x & 63;
    int i0 = blockIdx.x * 64;
    int w = blockIdx.y * 4 + wave;
    if (i0 >= M || w >= Wm) return;
    if (w < (int)blockIdx.x) return;   // lower triangle: all zero, never read

    int j = w * 64 + lane;           // j < Wm*64 <= N: safe to load
    float4 bj = sbox[j];
    float area2 = (bj.y - bj.x) * bj.w;
    int imax = min(64, M - i0);
    for (int it = 0; it < imax; ++it) {
        int i = i0 + it;
        float4 bi = sbox[i];         // uniform across the wave
        float inter_start = fmaxf(bi.x, bj.x);
        float inter_end   = fminf(bi.y, bj.y);
        float inter_len   = fmaxf(inter_end - inter_start, 0.0f);
        float inter_h     = fminf(bi.w, bj.w);
        float inter_area  = inter_len * inter_h;
        float area1       = (bi.y - bi.x) * bi.w;
        float union_area  = area1 + area2 - inter_area;
        float iou         = inter_area / union_area;
        float peak_dist   = fabsf(bi.z - bj.z);
        float union_start = fminf(bi.x, bj.x);
        float union_end   = fmaxf(bi.y, bj.y);
        float union_dist  = fabsf(union_end - union_start);
        float piou        = iou - peak_dist / union_dist;
        bool bit = (j < M) && (j > i) && (piou > PIOU_THRESH);
        u64 bal = __ballot(bit);
        if (lane == 0) mask[(size_t)i * WROW + w] = bal;
    }
}

// ---------------------------------------------------------------------------
// K3: sequential greedy resolution. ONE workgroup, 16 waves.
// 256-rank chunks (4 words). Wave 0 holds the 256x(4 word) diagonal block in
// VGPRs (double-buffered rsA/rsB; next chunk's loads issued BEFORE resolving
// the current one, so latency drains under compute). Cascade of 4 sub-resolves
// with pend[] carrying intra-chunk cross-word suppression via readlane.
// OR phase: thread (w, slice) ORs kept rows' word w in registers (coalesced,
// pipelined), then one LDS atomicOr pair.
// ---------------------------------------------------------------------------
__device__ inline u64 readlane64(u64 v, int b) {
    u32 lo = (u32)__builtin_amdgcn_readlane((int)(u32)v, b);
    u32 hi = (u32)__builtin_amdgcn_readlane((int)(u32)(v >> 32), b);
    return ((u64)hi << 32) | lo;
}

__device__ inline void load_diag(u64 (&rs)[4][4], const u64* __restrict__ mask,
                                 int WROW, int Wm, int M, int cc, int C, int lane) {
#pragma unroll
    for (int s = 0; s < 4; ++s) {
        int row = 256 * cc + 64 * s + lane;
        const u64* rowp = mask + (size_t)row * WROW;
#pragma unroll
        for (int u = 0; u < 4; ++u) {
            int w = 4 * cc + u;
            rs[s][u] = (u >= s && cc < C && row < M && w < Wm) ? rowp[w] : 0ull;
        }
    }
}

struct NmsShared {
    u32 R32[512];      // removed bitset, 2 u32 per word
    u32 rows_l[256];   // kept row ids this chunk
    u32 kcnt;
};

__device__ inline void step_chunk(u64 (&cur)[4][4], u64 (&nxt)[4][4], int c,
                                  const u64* __restrict__ mask, u64* __restrict__ keepm,
                                  NmsShared& sh, int WROW, int Wm, int M, int C,
                                  int tid, int wave, int lane) {
    if (wave == 0) {
        // issue next chunk's diagonal loads FIRST (latency hides under resolve)
        load_diag(nxt, mask, WROW, Wm, M, c + 1, C, lane);

        if (c < C) {
            u64 pend[4] = {0ull, 0ull, 0ull, 0ull};
            u32 kbase = 0;
#pragma unroll
            for (int s = 0; s < 4; ++s) {
                int w = 4 * c + s;
                bool active = (w < Wm);
                int base = 256 * c + 64 * s;
                int rem = M - base;
                u64 validm = (rem >= 64) ? ~0ull : ((rem <= 0) ? 0ull : ((1ull << rem) - 1ull));
                u64 removed = active
                    ? ((((u64)sh.R32[2 * w + 1] << 32) | sh.R32[2 * w]) | pend[s])
                    : ~0ull;
                u64 alive = ~removed & validm;
                u64 kept = 0;
                while (alive) {
                    int b = __builtin_ctzll(alive);
                    kept |= 1ull << b;
                    u64 r0 = readlane64(cur[s][s], b);
                    alive &= ~(r0 | (1ull << b));
#pragma unroll
                    for (int u = s + 1; u < 4; ++u)
                        pend[u] |= readlane64(cur[s][u], b);
                }
                u32 prefix = (u32)__builtin_popcountll(kept & ((1ull << lane) - 1ull));
                if ((kept >> lane) & 1ull) sh.rows_l[kbase + prefix] = (u32)(base + lane);
                kbase += (u32)__builtin_popcountll(kept);
                if (lane == 0 && active) keepm[w] = kept;
            }
            if (lane == 0) sh.kcnt = kbase;
        } else if (lane == 0) {
            sh.kcnt = 0;
        }
    }
    __syncthreads();

    // ---- OR phase: fold kept rows' words (4(c+1) .. Wm-1) into R ----
    int K = (int)sh.kcnt;
    int wbase = 4 * (c + 1);
    if (c < C && K > 0) {
        int slice = tid >> 7;                       // 8 slices over kept rows
        for (int widx = tid & 127; widx < Wm - wbase; widx += 128) {
            int w = wbase + widx;
            u64 v = 0;
            for (int k = slice; k < K; k += 8)
                v |= mask[(size_t)sh.rows_l[k] * WROW + w];
            if (v) {
                atomicOr(&sh.R32[2 * w], (u32)v);
                atomicOr(&sh.R32[2 * w + 1], (u32)(v >> 32));
            }
        }
    }
    __syncthreads();
}

__global__ void __launch_bounds__(1024) nms_seq_kernel(const u64* __restrict__ mask,
                                                       const u32* __restrict__ Mptr,
                                                       u64* __restrict__ keepm, int WROW) {
    __shared__ NmsShared sh;
    int tid = threadIdx.x;
    int wave = tid >> 6;
    int lane = tid & 63;
    int M = (int)*Mptr;
    int Wm = (M + 63) >> 6;
    int C = (Wm + 3) >> 2;          // number of 256-rank chunks

    u64 rsA[4][4], rsB[4][4];

    if (tid < 512) sh.R32[tid] = 0;
    if (wave == 0) load_diag(rsA, mask, WROW, Wm, M, 0, C, lane);
    __syncthreads();

    for (int c = 0; c < C; c += 2) {
        step_chunk(rsA, rsB, c,     mask, keepm, sh, WROW, Wm, M, C, tid, wave, lane);
        step_chunk(rsB, rsA, c + 1, mask, keepm, sh, WROW, Wm, M, C, tid, wave, lane);
    }
}

// ---------------------------------------------------------------------------
// K4: out[r] = sorted geometry * keep bit (exact 0/1 multiply).
// ---------------------------------------------------------------------------
__global__ void out_kernel(const float4* __restrict__ sbox, const u64* __restrict__ keepm,
                           float4* __restrict__ out, int N) {
    int r = blockIdx.x * 256 + threadIdx.x;
    if (r >= N) return;
    u64 w = keepm[r >> 6];
    float k = (float)((w >> (r & 63)) & 1ull);
    float4 v = sbox[r];
    out[r] = make_float4(v.x * k, v.y * k, v.z * k, v.w * k);
}

// ---------------------------------------------------------------------------
extern "C" void kernel_launch(void* const* d_in, const int* in_sizes, int n_in,
                              void* d_out, int out_size, void* d_ws, size_t ws_size,
                              hipStream_t stream) {
    const float* in = (const float*)d_in[0];
    int N = in_sizes[0] / 5;          // 16384
    int WROW = (N + 63) >> 6;         // 256 words per mask row

    char* ws = (char*)d_ws;
    u64* mask = (u64*)ws;                                   // N * WROW * 8 = 32 MB
    size_t maskBytes = (size_t)N * WROW * sizeof(u64);
    float4* sbox = (float4*)(ws + maskBytes);               // N * 16 = 256 KB
    u64* keepm = (u64*)(ws + maskBytes + (size_t)N * 16);   // WROW * 8 = 2 KB
    u32* rank = (u32*)((char*)keepm + (size_t)WROW * 8);    // N * 4
    u32* Mctr = rank + N;                                   // 4 B

    // zero keepm + rank + Mctr in one contiguous memset (ws is poisoned 0xAA)
    hipMemsetAsync(keepm, 0, (size_t)WROW * 8 + (size_t)N * 4 + 4, stream);

    dim3 rgrid(N / 256, N / 2048);
    rank_kernel<<<rgrid, 256, 0, stream>>>(in, rank, N);

    scatter_kernel<<<N / 256, 256, 0, stream>>>(in, rank, sbox, Mctr, N);

    dim3 mgrid(N / 64, (WROW + 3) / 4);
    mask_kernel<<<mgrid, 256, 0, stream>>>(sbox, Mctr, mask, N, WROW);

    nms_seq_kernel<<<1, 1024, 0, stream>>>(mask, Mctr, keepm, WROW);

    out_kernel<<<N / 256, 256, 0, stream>>>(sbox, keepm, (float4*)d_out, N);
}

// Round 4
// 479.167 us; speedup vs baseline: 6.5771x; 1.2656x over previous
//
#include <hip/hip_runtime.h>
#include <stdint.h>

typedef uint16_t u16;
typedef uint32_t u32;
typedef uint64_t u64;

#define CONF_THRESH 0.5f
#define PIOU_THRESH 0.5f

// ---------------------------------------------------------------------------
// K1a: rank by (conf desc, idx asc) via O(N^2) counting. key = conf_bits<<32 | ~idx.
// ---------------------------------------------------------------------------
__global__ void rank_kernel(const float* __restrict__ in, u32* __restrict__ rank, int N) {
    __shared__ u64 keys[2048];
    int t = threadIdx.x;
    int i = blockIdx.x * 256 + t;
    int j0 = blockIdx.y * 2048;
    for (int k = t; k < 2048; k += 256) {
        int j = j0 + k;
        u64 key = 0;
        if (j < N) {
            u32 cb = __float_as_uint(in[(size_t)j * 5]);
            key = ((u64)cb << 32) | (u64)(0xFFFFFFFFu - (u32)j);
        }
        keys[k] = key;
    }
    __syncthreads();
    if (i >= N) return;
    u32 cbi = __float_as_uint(in[(size_t)i * 5]);
    u64 mykey = ((u64)cbi << 32) | (u64)(0xFFFFFFFFu - (u32)i);
    int cnt = 0;
    for (int k = 0; k < 2048; ++k) cnt += (keys[k] > mykey) ? 1 : 0;
    if (cnt) atomicAdd(&rank[i], (u32)cnt);
}

// ---------------------------------------------------------------------------
// K1b: scatter boxes into sorted order (geometry only) + count valid M.
// ---------------------------------------------------------------------------
__global__ void scatter_kernel(const float* __restrict__ in, const u32* __restrict__ rank,
                               float4* __restrict__ sbox, u32* __restrict__ Mctr, int N) {
    int i = blockIdx.x * 256 + threadIdx.x;
    if (i >= N) return;
    float c = in[(size_t)i * 5 + 0];
    float s = in[(size_t)i * 5 + 1];
    float e = in[(size_t)i * 5 + 2];
    float p = in[(size_t)i * 5 + 3];
    float h = in[(size_t)i * 5 + 4];
    u32 r = rank[i];
    sbox[r] = make_float4(s, e, p, h);
    if (c > CONF_THRESH) atomicAdd(Mctr, 1u);
}

// ---------------------------------------------------------------------------
// K2: suppression bit matrix (upper triangle only).
// ---------------------------------------------------------------------------
__global__ void mask_kernel(const float4* __restrict__ sbox, const u32* __restrict__ Mptr,
                            u64* __restrict__ mask, int N, int WROW) {
#pragma clang fp contract(off)
    int M = (int)*Mptr;
    int Wm = (M + 63) >> 6;
    int wave = threadIdx.x >> 6;
    int lane = threadIdx.x & 63;
    int i0 = blockIdx.x * 64;
    int w = blockIdx.y * 4 + wave;
    if (i0 >= M || w >= Wm) return;
    if (w < (int)blockIdx.x) return;

    int j = w * 64 + lane;
    float4 bj = sbox[j];
    float area2 = (bj.y - bj.x) * bj.w;
    int imax = min(64, M - i0);
    for (int it = 0; it < imax; ++it) {
        int i = i0 + it;
        float4 bi = sbox[i];
        float inter_start = fmaxf(bi.x, bj.x);
        float inter_end   = fminf(bi.y, bj.y);
        float inter_len   = fmaxf(inter_end - inter_start, 0.0f);
        float inter_h     = fminf(bi.w, bj.w);
        float inter_area  = inter_len * inter_h;
        float area1       = (bi.y - bi.x) * bi.w;
        float union_area  = area1 + area2 - inter_area;
        float iou         = inter_area / union_area;
        float peak_dist   = fabsf(bi.z - bj.z);
        float union_start = fminf(bi.x, bj.x);
        float union_end   = fmaxf(bi.y, bj.y);
        float union_dist  = fabsf(union_end - union_start);
        float piou        = iou - peak_dist / union_dist;
        bool bit = (j < M) && (j > i) && (piou > PIOU_THRESH);
        u64 bal = __ballot(bit);
        if (lane == 0) mask[(size_t)i * WROW + w] = bal;
    }
}

// ---------------------------------------------------------------------------
// K3: sequential greedy resolution. ONE workgroup, 16 waves, 256-rank chunks.
// No incremental removed-bitset: at each chunk, the next chunk's 4 R-words are
// recomputed as OR over ALL kept rows so far (rows_all, LDS u16). All loads in
// a chunk are independent (batched 4-wide per thread), combined with a stride-4
// wave shuffle-OR reduce + 8 LDS atomics. Diagonal block staged into LDS by
// waves 1-15 (1 load/thread, double-buffered) so wave 0's resolve chain never
// touches global memory.
// ---------------------------------------------------------------------------
__device__ inline u64 readlane64(u64 v, int b) {
    u32 lo = (u32)__builtin_amdgcn_readlane((int)(u32)v, b);
    u32 hi = (u32)__builtin_amdgcn_readlane((int)(u32)(v >> 32), b);
    return ((u64)hi << 32) | lo;
}

__device__ inline u64 shfl_down64(u64 v, int off) {
    u32 lo = (u32)__shfl_down((int)(u32)v, off, 64);
    u32 hi = (u32)__shfl_down((int)(u32)(v >> 32), off, 64);
    return ((u64)hi << 32) | lo;
}

struct NmsShared {
    u64 ddiag[2][256][4];   // 16 KB: double-buffered 256-row diagonal block
    u32 R[2][8];            // double-buffered next-4-words removed bits
    u32 ka;                 // total kept rows so far
    u16 rows_all[16384];    // 32 KB: all kept row ids
};

__device__ inline void stage_one(NmsShared& sh, const u64* __restrict__ mask,
                                 int WROW, int Wm, int M, int cc, int C, int idx) {
    int rl = idx >> 2, u = idx & 3, s = rl >> 6;
    int row = 256 * cc + rl;
    int w = 4 * cc + u;
    u64 v = 0;
    if (cc < C && u >= s && row < M && w < Wm)
        v = mask[(size_t)row * WROW + w];
    sh.ddiag[cc & 1][rl][u] = v;
}

__device__ inline void step_chunk(int c, const u64* __restrict__ mask, u64* __restrict__ keepm,
                                  NmsShared& sh, int WROW, int Wm, int M, int C,
                                  int tid, int wave, int lane) {
    int p = c & 1;
    if (wave == 0) {
        // resolve chunk c from LDS diag + LDS R[p]
        u64 pend[4] = {0ull, 0ull, 0ull, 0ull};
        u32 kb = sh.ka;
#pragma unroll
        for (int s = 0; s < 4; ++s) {
            u64 curs[4];
#pragma unroll
            for (int u = 0; u < 4; ++u) curs[u] = sh.ddiag[p][64 * s + lane][u];
            int w = 4 * c + s;
            bool active = (w < Wm);
            int base = 256 * c + 64 * s;
            int rem = M - base;
            u64 validm = (rem >= 64) ? ~0ull : ((rem <= 0) ? 0ull : ((1ull << rem) - 1ull));
            u64 removed = active
                ? ((((u64)sh.R[p][2 * s + 1] << 32) | sh.R[p][2 * s]) | pend[s])
                : ~0ull;
            u64 alive = ~removed & validm;
            u64 kept = 0;
            while (alive) {
                int b = __builtin_ctzll(alive);
                kept |= 1ull << b;
                u64 r0 = readlane64(curs[s], b);
                alive &= ~(r0 | (1ull << b));
#pragma unroll
                for (int u = s + 1; u < 4; ++u) pend[u] |= readlane64(curs[u], b);
            }
            u32 prefix = (u32)__builtin_popcountll(kept & ((1ull << lane) - 1ull));
            if ((kept >> lane) & 1ull) sh.rows_all[kb + prefix] = (u16)(base + lane);
            kb += (u32)__builtin_popcountll(kept);
            if (lane == 0 && active) keepm[w] = kept;
        }
        if (lane == 0) sh.ka = kb;
    } else {
        // waves 1-15: zero next R + stage chunk c+1's diagonal (1-2 loads each)
        if (wave == 1 && lane < 8) sh.R[p ^ 1][lane] = 0;
        int idx = tid - 64;
        stage_one(sh, mask, WROW, Wm, M, c + 1, C, idx);
        if (idx < 64) stage_one(sh, mask, WROW, Wm, M, c + 1, C, idx + 960);
    }
    __syncthreads();

    // OR phase: R[p^1][0..3 words] = OR over all kept rows of their (next-chunk) words
    if (c + 1 < C) {
        int KA = (int)sh.ka;
        int wb = 4 * (c + 1);
        int total = KA * 4;
        u64 vacc = 0;
        for (int basei = 0; basei < total; basei += 4096) {
            int i0 = basei + tid;
            u64 v0 = 0, v1 = 0, v2 = 0, v3 = 0;
            if (i0 < total) { int w = wb + (i0 & 3); if (w < Wm) v0 = mask[(size_t)sh.rows_all[i0 >> 2] * WROW + w]; }
            int i1 = i0 + 1024;
            if (i1 < total) { int w = wb + (i1 & 3); if (w < Wm) v1 = mask[(size_t)sh.rows_all[i1 >> 2] * WROW + w]; }
            int i2 = i0 + 2048;
            if (i2 < total) { int w = wb + (i2 & 3); if (w < Wm) v2 = mask[(size_t)sh.rows_all[i2 >> 2] * WROW + w]; }
            int i3 = i0 + 3072;
            if (i3 < total) { int w = wb + (i3 & 3); if (w < Wm) v3 = mask[(size_t)sh.rows_all[i3 >> 2] * WROW + w]; }
            vacc |= (v0 | v1) | (v2 | v3);
        }
        // stride-4-preserving wave OR reduce: lanes 0..3 end with word classes 0..3
        for (int off = 4; off < 64; off <<= 1) vacc |= shfl_down64(vacc, off);
        if (lane < 4 && vacc) {
            atomicOr(&sh.R[p ^ 1][2 * lane],     (u32)vacc);
            atomicOr(&sh.R[p ^ 1][2 * lane + 1], (u32)(vacc >> 32));
        }
    }
    __syncthreads();
}

__global__ void __launch_bounds__(1024) nms_seq_kernel(const u64* __restrict__ mask,
                                                       const u32* __restrict__ Mptr,
                                                       u64* __restrict__ keepm, int WROW) {
    __shared__ NmsShared sh;
    int tid = threadIdx.x;
    int wave = tid >> 6;
    int lane = tid & 63;
    int M = (int)*Mptr;
    int Wm = (M + 63) >> 6;
    int C = (Wm + 3) >> 2;

    if (tid == 0) sh.ka = 0;
    if (tid < 16) sh.R[tid >> 3][tid & 7] = 0;
    stage_one(sh, mask, WROW, Wm, M, 0, C, tid);   // chunk 0 diag, all threads
    __syncthreads();

    for (int c = 0; c < C; ++c)
        step_chunk(c, mask, keepm, sh, WROW, Wm, M, C, tid, wave, lane);
}

// ---------------------------------------------------------------------------
// K4: out[r] = sorted geometry * keep bit (exact 0/1 multiply).
// ---------------------------------------------------------------------------
__global__ void out_kernel(const float4* __restrict__ sbox, const u64* __restrict__ keepm,
                           float4* __restrict__ out, int N) {
    int r = blockIdx.x * 256 + threadIdx.x;
    if (r >= N) return;
    u64 w = keepm[r >> 6];
    float k = (float)((w >> (r & 63)) & 1ull);
    float4 v = sbox[r];
    out[r] = make_float4(v.x * k, v.y * k, v.z * k, v.w * k);
}

// ---------------------------------------------------------------------------
extern "C" void kernel_launch(void* const* d_in, const int* in_sizes, int n_in,
                              void* d_out, int out_size, void* d_ws, size_t ws_size,
                              hipStream_t stream) {
    const float* in = (const float*)d_in[0];
    int N = in_sizes[0] / 5;          // 16384
    int WROW = (N + 63) >> 6;         // 256 words per mask row

    char* ws = (char*)d_ws;
    u64* mask = (u64*)ws;                                   // N * WROW * 8 = 32 MB
    size_t maskBytes = (size_t)N * WROW * sizeof(u64);
    float4* sbox = (float4*)(ws + maskBytes);               // N * 16 = 256 KB
    u64* keepm = (u64*)(ws + maskBytes + (size_t)N * 16);   // WROW * 8 = 2 KB
    u32* rank = (u32*)((char*)keepm + (size_t)WROW * 8);    // N * 4
    u32* Mctr = rank + N;                                   // 4 B

    // zero keepm + rank + Mctr in one contiguous memset (ws is poisoned 0xAA)
    hipMemsetAsync(keepm, 0, (size_t)WROW * 8 + (size_t)N * 4 + 4, stream);

    dim3 rgrid(N / 256, N / 2048);
    rank_kernel<<<rgrid, 256, 0, stream>>>(in, rank, N);

    scatter_kernel<<<N / 256, 256, 0, stream>>>(in, rank, sbox, Mctr, N);

    dim3 mgrid(N / 64, (WROW + 3) / 4);
    mask_kernel<<<mgrid, 256, 0, stream>>>(sbox, Mctr, mask, N, WROW);

    nms_seq_kernel<<<1, 1024, 0, stream>>>(mask, Mctr, keepm, WROW);

    out_kernel<<<N / 256, 256, 0, stream>>>(sbox, keepm, (float4*)d_out, N);
}